// Round 6
// baseline (141.471 us; speedup 1.0000x reference)
//
#include <hip/hip_runtime.h>
#include <math.h>
#include <utility>

#define BB 64
#define NN 512
#define DD 32
#define ZD 34            // DD + 2 (x..., t, y)
#define NE 595           // ZD*(ZD+1)/2 upper-triangular entries
#define WIN 8
#define NW 64            // NN / WIN windows
#define WACT 60          // active windows w = 4..63 (n <= 31 is rank-deficient -> 0)

// fused gram+scan geometry (entry-per-thread, 128-row segments)
#define SEG 4            // s-segments per batch (128 rows each)
#define RS 128           // rows per segment
#define KWS 16           // windows per segment
#define CH 4             // e-chunks per (b,seg)
#define ECH 149          // entries per chunk (4*149 >= 595)
#define PSTRIDE 17       // 16 exclusive in-segment snapshots + segment total

#define SPW 4            // solve: systems (waves) per workgroup

using f4 = __attribute__((ext_vector_type(4))) float;

// entry e -> (i,j), i <= j, row-major upper triangle of ZD x ZD
__device__ inline void ent2ij(int e, int& i, int& j) {
    int ii = 0, rem = e;
    while (rem >= ZD - ii) { rem -= (ZD - ii); ++ii; }
    i = ii; j = ii + rem;
}

// ---- recursive struct-of-scalars: SROA-guaranteed register residency ----
template<int N> struct Pack { Pack<N - 1> head; float v; };
template<> struct Pack<1> { float v; };
template<int I, int N> __device__ __forceinline__ float& pget(Pack<N>& p) {
    static_assert(I < N, "oob");
    if constexpr (I == N - 1) return p.v;
    else return pget<I, N - 1>(p.head);
}

__device__ __forceinline__ float rdlane(float x, int srclane) {
    return __int_as_float(__builtin_amdgcn_readlane(__float_as_int(x), srclane));
}
__device__ __forceinline__ float bperm(int byteaddr, float x) {
    return __int_as_float(__builtin_amdgcn_ds_bpermute(byteaddr, __float_as_int(x)));
}

// Fused window-partial + prefix-scan. Block = (b, s-segment, e-chunk).
// Each thread owns ONE triangle entry e and runs an fp64 prefix chain over the
// segment's 128 rows, emitting the 16 exclusive window snapshots (fp32) plus
// the segment total to P[b][seg][17][NE]. Folds output init: logs[.]=0
// everywhere and means=0 for n < 32.
__global__ __launch_bounds__(256) void dml_gram(const float* __restrict__ xtys,
                                                float* __restrict__ P,
                                                float* __restrict__ out) {
    const int t   = threadIdx.x;
    const int blk = blockIdx.x;                  // ((b*SEG + g)*CH + c)
    const int c   = blk % CH;
    const int bg  = blk / CH;
    const int g   = bg % SEG;
    const int b   = bg / SEG;

    const int gid = blk * 256 + t;
    if (gid < BB * NN) out[BB * NN + gid] = 0.0f;
    if (gid < BB * DD) out[(gid >> 5) * NN + (gid & 31)] = 0.0f;

    __shared__ float zs[RS * ZD];                // 17408 B
    const float* src = xtys + ((size_t)b * NN + (size_t)g * RS) * ZD;
    for (int u = t; u < RS * ZD; u += 256) zs[u] = src[u];
    __syncthreads();

    const int e = c * ECH + t;
    if (t < ECH && e < NE) {
        int i, j;
        ent2ij(e, i, j);
        float* pdst = P + (size_t)(b * SEG + g) * PSTRIDE * NE + e;
        double acc = 0.0;
#pragma unroll
        for (int k = 0; k < KWS; ++k) {
            pdst[k * NE] = (float)acc;           // exclusive: before window k's rows
#pragma unroll
            for (int s8 = 0; s8 < WIN; ++s8) {
                const float* row = &zs[(k * WIN + s8) * ZD];
                acc = fma((double)row[i], (double)row[j], acc);
            }
        }
        pdst[KWS * NE] = (float)acc;             // segment total
    }
}

// ---- solve: lane = COLUMN j of the symmetric bordered 42x42 matrix
// [[G0, W],[W^T, 0]], W = [x_1..x_8, Xtt0, Xty0]; A[r] = M[r][j].
// Symmetric-broadcast elimination: the trailing block stays symmetric under
// GE, so M[R][K] = M[K][R] = piv * t_R where t_R is LANE R's t. Step K:
// every lane writes t to tbW[lane] (1 ds_write), then reads t_{K+1..41} back
// via uniform-address float4 LDS reads (broadcast, conflict-free) and applies
// A[R] -= t_R * (piv * t_j). Replaces 42 readlanes/step with ~8 DS ops/step.
// Eliminated columns j < K have A[K] = 0 -> t = 0 -> no-op, as before.

template<int R> __device__ __forceinline__
float initval(int j, int off_j, int zoff, const float* snL, const float* zb) {
    constexpr int RC = (R < DD) ? (R * ZD - (R * (R - 1)) / 2 - R) : 0;
    if constexpr (R < DD) {
        float v = 0.0f;
        if (j < DD) {
            int idx = (R < j) ? (RC + j) : (off_j + R);
            v = snL[idx];
        } else if (j < DD + WIN) {
            v = zb[zoff + R];
        } else if (j == 40) {
            v = snL[RC + DD];                    // Xtt0[R]
        } else if (j == 41) {
            v = snL[RC + DD + 1];                // Xty0[R]
        }
        return v;
    } else if constexpr (R < DD + WIN) {
        return (j < DD) ? zb[(R - DD) * ZD + j] : 0.0f;
    } else if constexpr (R == 40) {
        return (j < DD) ? snL[off_j + DD] : 0.0f;
    } else {
        return (j < DD) ? snL[off_j + DD + 1] : 0.0f;
    }
}
template<int R> __device__ __forceinline__
void init_rec(Pack<42>& A, int j, int off_j, int zoff,
              const float* snL, const float* zb) {
    if constexpr (R < 42) {
        pget<R>(A) = initval<R>(j, off_j, zoff, snL, zb);
        init_rec<R + 1>(A, j, off_j, zoff, snL, zb);
    }
}

template<int K, int B> __device__ __forceinline__
void elim_fma4(Pack<42>& A, const float* tbW, float s) {
    if constexpr (B < 11) {                      // rows 4B..4B+3, up to 41
        if constexpr (4 * B + 3 > K) {
            f4 q = *(const f4*)(tbW + 4 * B);    // uniform addr -> broadcast read
            if constexpr (4*B+0 > K && 4*B+0 < 42) pget<4*B+0>(A) = fmaf(-q.x, s, pget<4*B+0>(A));
            if constexpr (4*B+1 > K && 4*B+1 < 42) pget<4*B+1>(A) = fmaf(-q.y, s, pget<4*B+1>(A));
            if constexpr (4*B+2 > K && 4*B+2 < 42) pget<4*B+2>(A) = fmaf(-q.z, s, pget<4*B+2>(A));
            if constexpr (4*B+3 > K && 4*B+3 < 42) pget<4*B+3>(A) = fmaf(-q.w, s, pget<4*B+3>(A));
        }
        elim_fma4<K, B + 1>(A, tbW, s);
    }
}
template<int K> __device__ __forceinline__
void elim_step(Pack<42>& A, float* tbW, int lane) {
    float piv  = rdlane(pget<K>(A), K);          // M[K][K], wave-uniform
    float invp = (piv > 1e-30f) ? 1.0f / piv : 0.0f;
    float t    = invp * pget<K>(A);              // t_j = M[K][j]/piv; 0 for done cols
    tbW[lane]  = t;                              // publish t (DS in-order per wave)
    float s    = piv * t;                        // so A[R] -= t_R * s = M[R][K]*t_j
    elim_fma4<K, (K + 1) / 4>(A, tbW, s);
}
template<int... Ks> __device__ __forceinline__
void elim_all(Pack<42>& A, float* tbW, int lane,
              std::integer_sequence<int, Ks...>) {
    ((elim_step<Ks>(A, tbW, lane)), ...);
}

template<int R> __device__ __forceinline__
void kdump(Pack<42>& A, float* Kl, int c) {      // lanes 32..41: column c of K
    if constexpr (R < DD + 10) {
        if constexpr (R >= DD)
            Kl[(R - DD) * 10 + c] = -pget<R>(A);
        kdump<R + 1>(A, Kl, c);
    }
}

// ---- row-parallel 8x8 GJ: lane = (sys, row) = (lane>>3, lane&7). Each lane
// holds ONE row (12 floats) in registers; pivot-row broadcast via ds_bpermute
// within the 8-lane group. Inactive rows (row > sys) are identity rows with
// zero RHS -> f = 0 forever, contribute exactly 0.
template<int L> __device__ __forceinline__
void tinit(Pack<12>& T, int row, int sys, const float* Kl, const float* zb) {
    if constexpr (L < 12) {
        float v;
        if constexpr (L < 8) {
            float kij = (row <= sys && L <= sys) ? Kl[row * 10 + L] : 0.0f;
            v = kij + ((row == L) ? 1.0f : 0.0f);
        } else if constexpr (L == 8)  v = (row <= sys) ? Kl[row * 10 + 8] : 0.0f;       // KUp
        else if constexpr (L == 9)    v = (row <= sys) ? zb[row * ZD + DD] : 0.0f;      // t_i
        else if constexpr (L == 10)   v = (row <= sys) ? Kl[row * 10 + 9] : 0.0f;       // KUq
        else                          v = (row <= sys) ? zb[row * ZD + DD + 1] : 0.0f;  // y_i
        pget<L>(T) = v;
        tinit<L + 1>(T, row, sys, Kl, zb);
    }
}
template<int K, int J> __device__ __forceinline__
void gjp_cols(Pack<12>& T, float f, int pb) {
    if constexpr (J < 12) {
        float pk = bperm(pb + 4 * K, pget<J>(T));   // pivot row K, col J
        pget<J>(T) = fmaf(-f, pk, pget<J>(T));
        gjp_cols<K, J + 1>(T, f, pb);
    }
}
template<int K> __device__ __forceinline__
void gjp_step(Pack<12>& T, int pb, int row, float& diag) {
    float pkK  = bperm(pb + 4 * K, pget<K>(T));     // M[K][K] of own system
    float invp = (pkK > 1e-30f || pkK < -1e-30f) ? 1.0f / pkK : 0.0f;
    float f    = (row == K) ? 0.0f : pget<K>(T) * invp;
    gjp_cols<K, K + 1>(T, f, pb);
    if (row == K) diag = pget<K>(T);                // T[K][K] final after step K
}
template<int... Ks> __device__ __forceinline__
void gjp_all(Pack<12>& T, int pb, int row, float& diag,
             std::integer_sequence<int, Ks...>) {
    ((gjp_step<Ks>(T, pb, row, diag)), ...);
}

// FOUR systems per 256-thread workgroup: wave wid owns system
// id = blockIdx.x*4 + wid = (b, w>=4), with private per-wave LDS slices (no
// __syncthreads: DS pipe is in-order per wave; slices are not shared).
// Snapshot Sn[w] = piece[g][k] + sum_{g'<g} total[g'], g=w>>4, k=w&15.
// Symmetric-broadcast elimination -> K = W^T G0^-1 W (10x10), then
// row-parallel GJ across all 64 lanes (8 sub-systems x 8 rows).
//   den = Stt0 - Kpp + sum_i (KpU_i - t_i)(s1_i - s2_i), s1=S^-1 KUp, s2=S^-1 t
//   num = Sty0 - Kpq + sum_i (KpU_i - t_i)(r1_i - r2_i), r1=S^-1 KUq, r2=S^-1 y
__global__ __launch_bounds__(256) void dml_solve(const float* __restrict__ xtys,
                                                 const float* __restrict__ P,
                                                 float* __restrict__ out) {
    const int wid  = threadIdx.x >> 6;
    const int lane = threadIdx.x & 63;
    const int id   = blockIdx.x * SPW + wid;   // 0 .. BB*WACT-1
    const int w    = (id % WACT) + 4;
    const int b    = id / WACT;
    const int g    = w >> 4;
    const int k    = w & 15;

    __shared__ float snL[SPW][NE];
    __shared__ float zb[SPW][WIN * ZD];
    __shared__ float Kl[SPW][100];       // K = W^T G0^-1 W (10x10)
    __shared__ alignas(16) float tb[SPW][64];   // per-step t-vector broadcast
    float* snW = snL[wid];
    float* zbW = zb[wid];
    float* KlW = Kl[wid];
    float* tbW = tb[wid];

    const float* pb_  = P + (size_t)b * SEG * PSTRIDE * NE;
    const float* src  = xtys + ((size_t)b * NN + (size_t)w * WIN) * ZD;
    for (int u = lane; u < NE; u += 64) {
        float v = pb_[(size_t)(g * PSTRIDE + k) * NE + u];
        for (int g2 = 0; g2 < g; ++g2)
            v += pb_[(size_t)(g2 * PSTRIDE + KWS) * NE + u];
        snW[u] = v;
    }
    for (int u = lane; u < WIN * ZD; u += 64) zbW[u] = src[u];
    // no __syncthreads: same-wave LDS producer/consumer, DS pipe is in-order

    const int j     = lane;
    const int off_j = j * (ZD - 1) - (j * (j - 1)) / 2;   // eidx(j, R) = off_j + R
    const int zoff  = (j - DD) * ZD;

    Pack<42> A;
    init_rec<0>(A, j, off_j, zoff, snW, zbW);  // lanes >= 42 get zeros

    elim_all(A, tbW, lane, std::make_integer_sequence<int, DD>{});

    if (lane >= DD && lane < DD + 10) kdump<0>(A, KlW, lane - DD);
    // no __syncthreads: kdump (DS writes) -> tinit (DS reads) same wave, in-order

    const int sys = lane >> 3;           // system index: n = 8w + sys
    const int row = lane & 7;
    const int pbB = (threadIdx.x & ~7) << 2;   // byte addr base of own 8-lane group

    Pack<12> T;
    tinit<0>(T, row, sys, KlW, zbW);
    float diag = 1.0f;
    gjp_all(T, pbB, row, diag, std::make_integer_sequence<int, 8>{});

    // per-row contribution; inactive rows (row > sys) have zero RHS -> 0
    float dinv = (diag > 1e-30f || diag < -1e-30f) ? 1.0f / diag : 0.0f;
    double s1 = (double)(pget<8>(T) * dinv);
    double s2 = (double)(pget<9>(T) * dinv);
    double r1 = (double)(pget<10>(T) * dinv);
    double r2 = (double)(pget<11>(T) * dinv);
    double gg = (double)KlW[80 + row] - (double)zbW[row * ZD + DD]; // KpU_i - t_i
    double cd = gg * (s1 - s2);
    double cn = gg * (r1 - r2);
#pragma unroll
    for (int m = 1; m < 8; m <<= 1) {
        cd += __shfl_xor(cd, m, 8);
        cn += __shfl_xor(cn, m, 8);
    }

    double Stt0 = (double)snW[592];
    double Sty0 = (double)snW[593];
    double den  = Stt0 - (double)KlW[88] + cd;  // Stt0 - Kpp + dterm
    double num  = Sty0 - (double)KlW[89] + cn;  // Sty0 - Kpq + nterm
    double val  = (den > 0.0) ? num / den : 0.0;
    if (!isfinite(val)) val = 0.0;
    if (row == 0) out[b * NN + w * WIN + sys] = (float)val;
}

extern "C" void kernel_launch(void* const* d_in, const int* in_sizes, int n_in,
                              void* d_out, int out_size, void* d_ws, size_t ws_size,
                              hipStream_t stream) {
    const float* xtys = (const float*)d_in[0];
    float* out = (float*)d_out;
    float* P = (float*)d_ws;   // [BB][SEG][17][NE] fp32 = 10.36 MB

    hipLaunchKernelGGL(dml_gram, dim3(BB * SEG * CH), dim3(256), 0, stream, xtys, P, out);
    hipLaunchKernelGGL(dml_solve, dim3(BB * WACT / SPW), dim3(256), 0, stream, xtys, P, out);
}

// Round 7
// 96.434 us; speedup vs baseline: 1.4670x; 1.4670x over previous
//
#include <hip/hip_runtime.h>
#include <math.h>
#include <utility>

#define BB 64
#define NN 512
#define DD 32
#define ZD 34            // DD + 2 (x..., t, y)
#define NE 595           // ZD*(ZD+1)/2 upper-triangular entries
#define WIN 8
#define NW 64            // NN / WIN windows
#define WACT 60          // active windows w = 4..63 (n <= 31 is rank-deficient -> 0)

// fused gram+scan geometry (entry-per-thread, 128-row segments)
#define SEG 4            // s-segments per batch (128 rows each)
#define RS 128           // rows per segment
#define KWS 16           // windows per segment
#define CH 4             // e-chunks per (b,seg)
#define ECH 149          // entries per chunk (4*149 >= 595)
#define PSTRIDE 17       // 16 exclusive in-segment snapshots + segment total

#define SPW 4            // solve: systems (waves) per workgroup

using f2 = __attribute__((ext_vector_type(2))) float;

// entry e -> (i,j), i <= j, row-major upper triangle of ZD x ZD
__device__ inline void ent2ij(int e, int& i, int& j) {
    int ii = 0, rem = e;
    while (rem >= ZD - ii) { rem -= (ZD - ii); ++ii; }
    i = ii; j = ii + rem;
}

// ---- recursive struct-of-scalars: SROA-guaranteed register residency ----
template<int N> struct Pack { Pack<N - 1> head; float v; };
template<> struct Pack<1> { float v; };
template<int I, int N> __device__ __forceinline__ float& pget(Pack<N>& p) {
    static_assert(I < N, "oob");
    if constexpr (I == N - 1) return p.v;
    else return pget<I, N - 1>(p.head);
}

// float2-pair variant (pair p = rows 2p, 2p+1) — invites v_pk_fma_f32
template<int N> struct PackP { PackP<N - 1> head; f2 v; };
template<> struct PackP<1> { f2 v; };
template<int I, int N> __device__ __forceinline__ f2& ppget(PackP<N>& p) {
    static_assert(I < N, "oob");
    if constexpr (I == N - 1) return p.v;
    else return ppget<I, N - 1>(p.head);
}
template<int R> __device__ __forceinline__ float prow(PackP<21>& p) {
    static_assert(R < 42, "oob");
    if constexpr (R & 1) return ppget<R / 2>(p).y;
    else                 return ppget<R / 2>(p).x;
}

__device__ __forceinline__ float rdlane(float x, int srclane) {
    return __int_as_float(__builtin_amdgcn_readlane(__float_as_int(x), srclane));
}
__device__ __forceinline__ float bperm(int byteaddr, float x) {
    return __int_as_float(__builtin_amdgcn_ds_bpermute(byteaddr, __float_as_int(x)));
}

// Fused window-partial + prefix-scan. Block = (b, s-segment, e-chunk).
// Each thread owns ONE triangle entry e. ILP form: 16 INDEPENDENT 8-fma fp64
// window partials + 16 serial adds (critical path ~100 cyc vs 128-deep serial
// chain before). Emits 16 exclusive window snapshots + segment total to
// P[b][seg][17][NE]. Folds output init: logs[.]=0, means=0 for n < 32.
__global__ __launch_bounds__(256) void dml_gram(const float* __restrict__ xtys,
                                                float* __restrict__ P,
                                                float* __restrict__ out) {
    const int t   = threadIdx.x;
    const int blk = blockIdx.x;                  // ((b*SEG + g)*CH + c)
    const int c   = blk % CH;
    const int bg  = blk / CH;
    const int g   = bg % SEG;
    const int b   = bg / SEG;

    const int gid = blk * 256 + t;
    if (gid < BB * NN) out[BB * NN + gid] = 0.0f;
    if (gid < BB * DD) out[(gid >> 5) * NN + (gid & 31)] = 0.0f;

    __shared__ float zs[RS * ZD];                // 17408 B
    const float* src = xtys + ((size_t)b * NN + (size_t)g * RS) * ZD;
    for (int u = t; u < RS * ZD; u += 256) zs[u] = src[u];
    __syncthreads();

    const int e = c * ECH + t;
    if (t < ECH && e < NE) {
        int i, j;
        ent2ij(e, i, j);
        float* pdst = P + (size_t)(b * SEG + g) * PSTRIDE * NE + e;
        double acc = 0.0;
#pragma unroll
        for (int k = 0; k < KWS; ++k) {
            pdst[k * NE] = (float)acc;           // exclusive: before window k's rows
            double wsum = 0.0;                   // independent chain per window
#pragma unroll
            for (int s8 = 0; s8 < WIN; ++s8) {
                const float* row = &zs[(k * WIN + s8) * ZD];
                wsum = fma((double)row[i], (double)row[j], wsum);
            }
            acc += wsum;
        }
        pdst[KWS * NE] = (float)acc;             // segment total
    }
}

// ---- solve: lane = COLUMN j of the symmetric bordered 42x42 matrix
// [[G0, W],[W^T, 0]], W = [x_1..x_8, Xtt0, Xty0]; A[r] = M[r][j], stored as
// 21 float2 pairs. Elimination step K: cross-lane values are wave-uniform
// (from lane K) -> v_readlane; each pair updated with one vector op
// (A2 -= fr2 * t2, packs to v_pk_fma_f32). Pair (K>>1) at even K also
// touches dead pivot row K — safe: pivot rows are only read (piv, t) BEFORE
// the updates of their own step, and never afterwards.

template<int R> __device__ __forceinline__
float initval(int j, int off_j, int zoff, const float* snL, const float* zb) {
    constexpr int RC = (R < DD) ? (R * ZD - (R * (R - 1)) / 2 - R) : 0;
    if constexpr (R < DD) {
        float v = 0.0f;
        if (j < DD) {
            int idx = (R < j) ? (RC + j) : (off_j + R);
            v = snL[idx];
        } else if (j < DD + WIN) {
            v = zb[zoff + R];
        } else if (j == 40) {
            v = snL[RC + DD];                    // Xtt0[R]
        } else if (j == 41) {
            v = snL[RC + DD + 1];                // Xty0[R]
        }
        return v;
    } else if constexpr (R < DD + WIN) {
        return (j < DD) ? zb[(R - DD) * ZD + j] : 0.0f;
    } else if constexpr (R == 40) {
        return (j < DD) ? snL[off_j + DD] : 0.0f;
    } else {
        return (j < DD) ? snL[off_j + DD + 1] : 0.0f;
    }
}
template<int P> __device__ __forceinline__
void init_rec(PackP<21>& A, int j, int off_j, int zoff,
              const float* snL, const float* zb) {
    if constexpr (P < 21) {
        f2 q;
        q.x = initval<2 * P>(j, off_j, zoff, snL, zb);
        q.y = initval<2 * P + 1>(j, off_j, zoff, snL, zb);
        ppget<P>(A) = q;
        init_rec<P + 1>(A, j, off_j, zoff, snL, zb);
    }
}

template<int K, int P> __device__ __forceinline__
void elim_pairs(PackP<21>& A, f2 t2) {
    if constexpr (P < 21) {
        f2 fr2;
        fr2.x = rdlane(prow<2 * P>(A), K);       // M[2P][K], wave-uniform
        fr2.y = rdlane(prow<2 * P + 1>(A), K);
        ppget<P>(A) -= fr2 * t2;                 // contract -> v_pk_fma_f32
        elim_pairs<K, P + 1>(A, t2);
    }
}
template<int K> __device__ __forceinline__
void elim_step(PackP<21>& A) {
    float piv  = rdlane(prow<K>(A), K);          // M[K][K]
    float invp = (piv > 1e-30f) ? 1.0f / piv : 0.0f;
    float t    = invp * prow<K>(A);              // invp*M[K][j]; 0 for done cols
    f2 t2; t2.x = t; t2.y = t;
    elim_pairs<K, (K + 1) / 2>(A, t2);
}
template<int... Ks> __device__ __forceinline__
void elim_all(PackP<21>& A, std::integer_sequence<int, Ks...>) {
    ((elim_step<Ks>(A)), ...);
}

template<int R> __device__ __forceinline__
void kdump(PackP<21>& A, float* Kl, int c) {     // lanes 32..41: column c of K
    if constexpr (R < DD + 10) {
        if constexpr (R >= DD)
            Kl[(R - DD) * 10 + c] = -prow<R>(A);
        kdump<R + 1>(A, Kl, c);
    }
}

// ---- row-parallel 8x8 GJ: lane = (sys, row) = (lane>>3, lane&7). Each lane
// holds ONE row (12 floats) in registers; pivot-row broadcast via ds_bpermute
// within the 8-lane group. Inactive rows (row > sys) are identity rows with
// zero RHS -> f = 0 forever, contribute exactly 0.
template<int L> __device__ __forceinline__
void tinit(Pack<12>& T, int row, int sys, const float* Kl, const float* zb) {
    if constexpr (L < 12) {
        float v;
        if constexpr (L < 8) {
            float kij = (row <= sys && L <= sys) ? Kl[row * 10 + L] : 0.0f;
            v = kij + ((row == L) ? 1.0f : 0.0f);
        } else if constexpr (L == 8)  v = (row <= sys) ? Kl[row * 10 + 8] : 0.0f;       // KUp
        else if constexpr (L == 9)    v = (row <= sys) ? zb[row * ZD + DD] : 0.0f;      // t_i
        else if constexpr (L == 10)   v = (row <= sys) ? Kl[row * 10 + 9] : 0.0f;       // KUq
        else                          v = (row <= sys) ? zb[row * ZD + DD + 1] : 0.0f;  // y_i
        pget<L>(T) = v;
        tinit<L + 1>(T, row, sys, Kl, zb);
    }
}
template<int K, int J> __device__ __forceinline__
void gjp_cols(Pack<12>& T, float f, int pb) {
    if constexpr (J < 12) {
        float pk = bperm(pb + 4 * K, pget<J>(T));   // pivot row K, col J
        pget<J>(T) = fmaf(-f, pk, pget<J>(T));
        gjp_cols<K, J + 1>(T, f, pb);
    }
}
template<int K> __device__ __forceinline__
void gjp_step(Pack<12>& T, int pb, int row, float& diag) {
    float pkK  = bperm(pb + 4 * K, pget<K>(T));     // M[K][K] of own system
    float invp = (pkK > 1e-30f || pkK < -1e-30f) ? 1.0f / pkK : 0.0f;
    float f    = (row == K) ? 0.0f : pget<K>(T) * invp;
    gjp_cols<K, K + 1>(T, f, pb);
    if (row == K) diag = pget<K>(T);                // T[K][K] final after step K
}
template<int... Ks> __device__ __forceinline__
void gjp_all(Pack<12>& T, int pb, int row, float& diag,
             std::integer_sequence<int, Ks...>) {
    ((gjp_step<Ks>(T, pb, row, diag)), ...);
}

// FOUR systems per 256-thread workgroup: wave wid owns system
// id = blockIdx.x*4 + wid = (b, w>=4), with private per-wave LDS slices (no
// __syncthreads: DS pipe is in-order per wave; slices are not shared).
// Snapshot Sn[w] = piece[g][k] + sum_{g'<g} total[g'], g=w>>4, k=w&15.
// Readlane-based packed-pair elimination -> K = W^T G0^-1 W (10x10), then
// row-parallel GJ across all 64 lanes (8 sub-systems x 8 rows).
//   den = Stt0 - Kpp + sum_i (KpU_i - t_i)(s1_i - s2_i), s1=S^-1 KUp, s2=S^-1 t
//   num = Sty0 - Kpq + sum_i (KpU_i - t_i)(r1_i - r2_i), r1=S^-1 KUq, r2=S^-1 y
__global__ __launch_bounds__(256) void dml_solve(const float* __restrict__ xtys,
                                                 const float* __restrict__ P,
                                                 float* __restrict__ out) {
    const int wid  = threadIdx.x >> 6;
    const int lane = threadIdx.x & 63;
    const int id   = blockIdx.x * SPW + wid;   // 0 .. BB*WACT-1
    const int w    = (id % WACT) + 4;
    const int b    = id / WACT;
    const int g    = w >> 4;
    const int k    = w & 15;

    __shared__ float snL[SPW][NE];
    __shared__ float zb[SPW][WIN * ZD];
    __shared__ float Kl[SPW][100];       // K = W^T G0^-1 W (10x10)
    float* snW = snL[wid];
    float* zbW = zb[wid];
    float* KlW = Kl[wid];

    const float* pb_  = P + (size_t)b * SEG * PSTRIDE * NE;
    const float* src  = xtys + ((size_t)b * NN + (size_t)w * WIN) * ZD;
    for (int u = lane; u < NE; u += 64) {
        float v = pb_[(size_t)(g * PSTRIDE + k) * NE + u];
        for (int g2 = 0; g2 < g; ++g2)
            v += pb_[(size_t)(g2 * PSTRIDE + KWS) * NE + u];
        snW[u] = v;
    }
    for (int u = lane; u < WIN * ZD; u += 64) zbW[u] = src[u];
    // no __syncthreads: same-wave LDS producer/consumer, DS pipe is in-order

    const int j     = lane;
    const int off_j = j * (ZD - 1) - (j * (j - 1)) / 2;   // eidx(j, R) = off_j + R
    const int zoff  = (j - DD) * ZD;

    PackP<21> A;
    init_rec<0>(A, j, off_j, zoff, snW, zbW);  // lanes >= 42 get zeros

    elim_all(A, std::make_integer_sequence<int, DD>{});

    if (lane >= DD && lane < DD + 10) kdump<0>(A, KlW, lane - DD);
    // no __syncthreads: kdump (DS writes) -> tinit (DS reads) same wave, in-order

    const int sys = lane >> 3;           // system index: n = 8w + sys
    const int row = lane & 7;
    const int pbB = (threadIdx.x & ~7) << 2;   // byte addr base of own 8-lane group

    Pack<12> T;
    tinit<0>(T, row, sys, KlW, zbW);
    float diag = 1.0f;
    gjp_all(T, pbB, row, diag, std::make_integer_sequence<int, 8>{});

    // per-row contribution; inactive rows (row > sys) have zero RHS -> 0
    float dinv = (diag > 1e-30f || diag < -1e-30f) ? 1.0f / diag : 0.0f;
    double s1 = (double)(pget<8>(T) * dinv);
    double s2 = (double)(pget<9>(T) * dinv);
    double r1 = (double)(pget<10>(T) * dinv);
    double r2 = (double)(pget<11>(T) * dinv);
    double gg = (double)KlW[80 + row] - (double)zbW[row * ZD + DD]; // KpU_i - t_i
    double cd = gg * (s1 - s2);
    double cn = gg * (r1 - r2);
#pragma unroll
    for (int m = 1; m < 8; m <<= 1) {
        cd += __shfl_xor(cd, m, 8);
        cn += __shfl_xor(cn, m, 8);
    }

    double Stt0 = (double)snW[592];
    double Sty0 = (double)snW[593];
    double den  = Stt0 - (double)KlW[88] + cd;  // Stt0 - Kpp + dterm
    double num  = Sty0 - (double)KlW[89] + cn;  // Sty0 - Kpq + nterm
    double val  = (den > 0.0) ? num / den : 0.0;
    if (!isfinite(val)) val = 0.0;
    if (row == 0) out[b * NN + w * WIN + sys] = (float)val;
}

extern "C" void kernel_launch(void* const* d_in, const int* in_sizes, int n_in,
                              void* d_out, int out_size, void* d_ws, size_t ws_size,
                              hipStream_t stream) {
    const float* xtys = (const float*)d_in[0];
    float* out = (float*)d_out;
    float* P = (float*)d_ws;   // [BB][SEG][17][NE] fp32 = 10.36 MB

    hipLaunchKernelGGL(dml_gram, dim3(BB * SEG * CH), dim3(256), 0, stream, xtys, P, out);
    hipLaunchKernelGGL(dml_solve, dim3(BB * WACT / SPW), dim3(256), 0, stream, xtys, P, out);
}

// Round 8
// 93.218 us; speedup vs baseline: 1.5176x; 1.0345x over previous
//
#include <hip/hip_runtime.h>
#include <math.h>
#include <utility>

#define BB 64
#define NN 512
#define DD 32
#define ZD 34            // DD + 2 (x..., t, y)
#define NE 595           // ZD*(ZD+1)/2 upper-triangular entries
#define WIN 8
#define NW 64            // NN / WIN windows
#define WACT 60          // active windows w = 4..63 (n <= 31 is rank-deficient -> 0)

// fused gram+scan geometry (entry-per-thread, 128-row segments)
#define SEG 4            // s-segments per batch (128 rows each)
#define RS 128           // rows per segment
#define KWS 16           // windows per segment
#define CH 4             // e-chunks per (b,seg)
#define ECH 149          // entries per chunk (4*149 >= 595)
#define PSTRIDE 17       // 16 exclusive in-segment snapshots + segment total

#define SPW 5            // solve: systems (waves) per WG; 3840/5 = 768 WGs = 3/CU exact

using f2 = __attribute__((ext_vector_type(2))) float;

// entry e -> (i,j), i <= j, row-major upper triangle of ZD x ZD
__device__ inline void ent2ij(int e, int& i, int& j) {
    int ii = 0, rem = e;
    while (rem >= ZD - ii) { rem -= (ZD - ii); ++ii; }
    i = ii; j = ii + rem;
}

// ---- recursive struct-of-scalars: SROA-guaranteed register residency ----
template<int N> struct Pack { Pack<N - 1> head; float v; };
template<> struct Pack<1> { float v; };
template<int I, int N> __device__ __forceinline__ float& pget(Pack<N>& p) {
    static_assert(I < N, "oob");
    if constexpr (I == N - 1) return p.v;
    else return pget<I, N - 1>(p.head);
}

// float2-pair variant (pair p = rows 2p, 2p+1)
template<int N> struct PackP { PackP<N - 1> head; f2 v; };
template<> struct PackP<1> { f2 v; };
template<int I, int N> __device__ __forceinline__ f2& ppget(PackP<N>& p) {
    static_assert(I < N, "oob");
    if constexpr (I == N - 1) return p.v;
    else return ppget<I, N - 1>(p.head);
}
template<int R> __device__ __forceinline__ float prow(PackP<21>& p) {
    static_assert(R < 42, "oob");
    if constexpr (R & 1) return ppget<R / 2>(p).y;
    else                 return ppget<R / 2>(p).x;
}

__device__ __forceinline__ float rdlane(float x, int srclane) {
    return __int_as_float(__builtin_amdgcn_readlane(__float_as_int(x), srclane));
}
__device__ __forceinline__ float bperm(int byteaddr, float x) {
    return __int_as_float(__builtin_amdgcn_ds_bpermute(byteaddr, __float_as_int(x)));
}

// Fused window-partial + prefix-scan. Block = (b, s-segment, e-chunk).
// Each thread owns ONE triangle entry e. ILP form: 16 INDEPENDENT 8-fma fp64
// window partials + 16 serial adds. Emits 16 exclusive window snapshots +
// segment total to P[b][seg][17][NE]. Folds output init: logs[.]=0, means=0
// for n < 32.
__global__ __launch_bounds__(256) void dml_gram(const float* __restrict__ xtys,
                                                float* __restrict__ P,
                                                float* __restrict__ out) {
    const int t   = threadIdx.x;
    const int blk = blockIdx.x;                  // ((b*SEG + g)*CH + c)
    const int c   = blk % CH;
    const int bg  = blk / CH;
    const int g   = bg % SEG;
    const int b   = bg / SEG;

    const int gid = blk * 256 + t;
    if (gid < BB * NN) out[BB * NN + gid] = 0.0f;
    if (gid < BB * DD) out[(gid >> 5) * NN + (gid & 31)] = 0.0f;

    __shared__ float zs[RS * ZD];                // 17408 B
    const float* src = xtys + ((size_t)b * NN + (size_t)g * RS) * ZD;
    for (int u = t; u < RS * ZD; u += 256) zs[u] = src[u];
    __syncthreads();

    const int e = c * ECH + t;
    if (t < ECH && e < NE) {
        int i, j;
        ent2ij(e, i, j);
        float* pdst = P + (size_t)(b * SEG + g) * PSTRIDE * NE + e;
        double acc = 0.0;
#pragma unroll
        for (int k = 0; k < KWS; ++k) {
            pdst[k * NE] = (float)acc;           // exclusive: before window k's rows
            double wsum = 0.0;                   // independent chain per window
#pragma unroll
            for (int s8 = 0; s8 < WIN; ++s8) {
                const float* row = &zs[(k * WIN + s8) * ZD];
                wsum = fma((double)row[i], (double)row[j], wsum);
            }
            acc += wsum;
        }
        pdst[KWS * NE] = (float)acc;             // segment total
    }
}

// ---- solve: lane = COLUMN j of the symmetric bordered 42x42 matrix
// [[G0, W],[W^T, 0]], W = [x_1..x_8, Xtt0, Xty0]; A[r] = M[r][j], stored as
// 21 float2 pairs. Elimination step K: cross-lane values are wave-uniform
// (from lane K) -> v_readlane; each pair updated with one vector op. Pair
// (K>>1) at even K also touches dead pivot row K — safe: pivot rows are only
// read (piv, t) BEFORE the updates of their own step, never afterwards.

template<int R> __device__ __forceinline__
float initval(int j, int off_j, int zoff, const float* snL, const float* zb) {
    constexpr int RC = (R < DD) ? (R * ZD - (R * (R - 1)) / 2 - R) : 0;
    if constexpr (R < DD) {
        float v = 0.0f;
        if (j < DD) {
            int idx = (R < j) ? (RC + j) : (off_j + R);
            v = snL[idx];
        } else if (j < DD + WIN) {
            v = zb[zoff + R];
        } else if (j == 40) {
            v = snL[RC + DD];                    // Xtt0[R]
        } else if (j == 41) {
            v = snL[RC + DD + 1];                // Xty0[R]
        }
        return v;
    } else if constexpr (R < DD + WIN) {
        return (j < DD) ? zb[(R - DD) * ZD + j] : 0.0f;
    } else if constexpr (R == 40) {
        return (j < DD) ? snL[off_j + DD] : 0.0f;
    } else {
        return (j < DD) ? snL[off_j + DD + 1] : 0.0f;
    }
}
template<int P> __device__ __forceinline__
void init_rec(PackP<21>& A, int j, int off_j, int zoff,
              const float* snL, const float* zb) {
    if constexpr (P < 21) {
        f2 q;
        q.x = initval<2 * P>(j, off_j, zoff, snL, zb);
        q.y = initval<2 * P + 1>(j, off_j, zoff, snL, zb);
        ppget<P>(A) = q;
        init_rec<P + 1>(A, j, off_j, zoff, snL, zb);
    }
}

template<int K, int P> __device__ __forceinline__
void elim_pairs(PackP<21>& A, f2 t2) {
    if constexpr (P < 21) {
        f2 fr2;
        fr2.x = rdlane(prow<2 * P>(A), K);       // M[2P][K], wave-uniform
        fr2.y = rdlane(prow<2 * P + 1>(A), K);
        ppget<P>(A) -= fr2 * t2;
        elim_pairs<K, P + 1>(A, t2);
    }
}
template<int K> __device__ __forceinline__
void elim_step(PackP<21>& A) {
    float piv  = rdlane(prow<K>(A), K);          // M[K][K]
    float invp = (piv > 1e-30f) ? 1.0f / piv : 0.0f;
    float t    = invp * prow<K>(A);              // invp*M[K][j]; 0 for done cols
    f2 t2; t2.x = t; t2.y = t;
    elim_pairs<K, (K + 1) / 2>(A, t2);
}
template<int... Ks> __device__ __forceinline__
void elim_all(PackP<21>& A, std::integer_sequence<int, Ks...>) {
    ((elim_step<Ks>(A)), ...);
}

template<int R> __device__ __forceinline__
void kdump(PackP<21>& A, float* Kl, int c) {     // lanes 32..41: column c of K
    if constexpr (R < DD + 10) {
        if constexpr (R >= DD)
            Kl[(R - DD) * 10 + c] = -prow<R>(A);
        kdump<R + 1>(A, Kl, c);
    }
}

// ---- row-parallel 8x8 GJ: lane = (sys, row) = (lane>>3, lane&7). Each lane
// holds ONE row (12 floats) in registers; pivot-row broadcast via ds_bpermute
// within the 8-lane group. Inactive rows (row > sys) are identity rows with
// zero RHS -> f = 0 forever, contribute exactly 0.
template<int L> __device__ __forceinline__
void tinit(Pack<12>& T, int row, int sys, const float* Kl, const float* zb) {
    if constexpr (L < 12) {
        float v;
        if constexpr (L < 8) {
            float kij = (row <= sys && L <= sys) ? Kl[row * 10 + L] : 0.0f;
            v = kij + ((row == L) ? 1.0f : 0.0f);
        } else if constexpr (L == 8)  v = (row <= sys) ? Kl[row * 10 + 8] : 0.0f;       // KUp
        else if constexpr (L == 9)    v = (row <= sys) ? zb[row * ZD + DD] : 0.0f;      // t_i
        else if constexpr (L == 10)   v = (row <= sys) ? Kl[row * 10 + 9] : 0.0f;       // KUq
        else                          v = (row <= sys) ? zb[row * ZD + DD + 1] : 0.0f;  // y_i
        pget<L>(T) = v;
        tinit<L + 1>(T, row, sys, Kl, zb);
    }
}
template<int K, int J> __device__ __forceinline__
void gjp_cols(Pack<12>& T, float f, int pb) {
    if constexpr (J < 12) {
        float pk = bperm(pb + 4 * K, pget<J>(T));   // pivot row K, col J
        pget<J>(T) = fmaf(-f, pk, pget<J>(T));
        gjp_cols<K, J + 1>(T, f, pb);
    }
}
template<int K> __device__ __forceinline__
void gjp_step(Pack<12>& T, int pb, int row, float& diag) {
    float pkK  = bperm(pb + 4 * K, pget<K>(T));     // M[K][K] of own system
    float invp = (pkK > 1e-30f || pkK < -1e-30f) ? 1.0f / pkK : 0.0f;
    float f    = (row == K) ? 0.0f : pget<K>(T) * invp;
    gjp_cols<K, K + 1>(T, f, pb);
    if (row == K) diag = pget<K>(T);                // T[K][K] final after step K
}
template<int... Ks> __device__ __forceinline__
void gjp_all(Pack<12>& T, int pb, int row, float& diag,
             std::integer_sequence<int, Ks...>) {
    ((gjp_step<Ks>(T, pb, row, diag)), ...);
}

// FIVE systems per 320-thread workgroup: wave wid owns system
// id = blockIdx.x*5 + wid = (b, w>=4), private per-wave LDS slices, no
// __syncthreads (DS pipe in-order per wave; slices not shared). 3840/5 = 768
// WGs = EXACTLY 3 per CU (and 96 per XCD): removes the 3-vs-4 WG/CU load
// imbalance tail seen at SPW=4 (960 WGs -> 3.75/CU).
// Snapshot Sn[w] = piece[g][k] + sum_{g'<g} total[g'], g=w>>4, k=w&15.
// Readlane packed-pair elimination -> K = W^T G0^-1 W (10x10), then
// row-parallel GJ across all 64 lanes (8 sub-systems x 8 rows).
//   den = Stt0 - Kpp + sum_i (KpU_i - t_i)(s1_i - s2_i), s1=S^-1 KUp, s2=S^-1 t
//   num = Sty0 - Kpq + sum_i (KpU_i - t_i)(r1_i - r2_i), r1=S^-1 KUq, r2=S^-1 y
__global__ __launch_bounds__(320) void dml_solve(const float* __restrict__ xtys,
                                                 const float* __restrict__ P,
                                                 float* __restrict__ out) {
    const int wid  = threadIdx.x >> 6;         // 0..4
    const int lane = threadIdx.x & 63;
    const int id   = blockIdx.x * SPW + wid;   // 0 .. BB*WACT-1 exactly
    const int w    = (id % WACT) + 4;
    const int b    = id / WACT;
    const int g    = w >> 4;
    const int k    = w & 15;

    __shared__ float snL[SPW][NE];
    __shared__ float zb[SPW][WIN * ZD];
    __shared__ float Kl[SPW][100];       // K = W^T G0^-1 W (10x10)
    float* snW = snL[wid];
    float* zbW = zb[wid];
    float* KlW = Kl[wid];

    const float* pb_  = P + (size_t)b * SEG * PSTRIDE * NE;
    const float* src  = xtys + ((size_t)b * NN + (size_t)w * WIN) * ZD;
    for (int u = lane; u < NE; u += 64) {
        float v = pb_[(size_t)(g * PSTRIDE + k) * NE + u];
        for (int g2 = 0; g2 < g; ++g2)
            v += pb_[(size_t)(g2 * PSTRIDE + KWS) * NE + u];
        snW[u] = v;
    }
    for (int u = lane; u < WIN * ZD; u += 64) zbW[u] = src[u];
    // no __syncthreads: same-wave LDS producer/consumer, DS pipe is in-order

    const int j     = lane;
    const int off_j = j * (ZD - 1) - (j * (j - 1)) / 2;   // eidx(j, R) = off_j + R
    const int zoff  = (j - DD) * ZD;

    PackP<21> A;
    init_rec<0>(A, j, off_j, zoff, snW, zbW);  // lanes >= 42 get zeros

    elim_all(A, std::make_integer_sequence<int, DD>{});

    if (lane >= DD && lane < DD + 10) kdump<0>(A, KlW, lane - DD);
    // no __syncthreads: kdump (DS writes) -> tinit (DS reads) same wave, in-order

    const int sys = lane >> 3;           // sub-system index: n = 8w + sys
    const int row = lane & 7;
    const int pbB = (lane & ~7) << 2;    // byte base of own 8-lane group (in-wave)

    Pack<12> T;
    tinit<0>(T, row, sys, KlW, zbW);
    float diag = 1.0f;
    gjp_all(T, pbB, row, diag, std::make_integer_sequence<int, 8>{});

    // per-row contribution; inactive rows (row > sys) have zero RHS -> 0
    float dinv = (diag > 1e-30f || diag < -1e-30f) ? 1.0f / diag : 0.0f;
    double s1 = (double)(pget<8>(T) * dinv);
    double s2 = (double)(pget<9>(T) * dinv);
    double r1 = (double)(pget<10>(T) * dinv);
    double r2 = (double)(pget<11>(T) * dinv);
    double gg = (double)KlW[80 + row] - (double)zbW[row * ZD + DD]; // KpU_i - t_i
    double cd = gg * (s1 - s2);
    double cn = gg * (r1 - r2);
#pragma unroll
    for (int m = 1; m < 8; m <<= 1) {
        cd += __shfl_xor(cd, m, 8);
        cn += __shfl_xor(cn, m, 8);
    }

    double Stt0 = (double)snW[592];
    double Sty0 = (double)snW[593];
    double den  = Stt0 - (double)KlW[88] + cd;  // Stt0 - Kpp + dterm
    double num  = Sty0 - (double)KlW[89] + cn;  // Sty0 - Kpq + nterm
    double val  = (den > 0.0) ? num / den : 0.0;
    if (!isfinite(val)) val = 0.0;
    if (row == 0) out[b * NN + w * WIN + sys] = (float)val;
}

extern "C" void kernel_launch(void* const* d_in, const int* in_sizes, int n_in,
                              void* d_out, int out_size, void* d_ws, size_t ws_size,
                              hipStream_t stream) {
    const float* xtys = (const float*)d_in[0];
    float* out = (float*)d_out;
    float* P = (float*)d_ws;   // [BB][SEG][17][NE] fp32 = 10.36 MB

    hipLaunchKernelGGL(dml_gram, dim3(BB * SEG * CH), dim3(256), 0, stream, xtys, P, out);
    hipLaunchKernelGGL(dml_solve, dim3(BB * WACT / SPW), dim3(320), 0, stream, xtys, P, out);
}